// Round 11
// baseline (955.150 us; speedup 1.0000x reference)
//
#include <hip/hip_runtime.h>
#include <hip/hip_bf16.h>

// PoolingAttention: B=64 N=197 C=768 H=12 D=64. fp32 in/out (runtime-detected).
// out = [B*N*C] attention output ++ [B*160] keep_index.
//
// R11: revert R10's global_load_lds (on gfx950 it bypasses the L2 reuse the
// XCD swizzle depends on: FETCH 38->745MB, 98->475us). Keep register-staged
// cached loads (R9) but with R10's transposed LDS layout so both ds_write
// and fragment ds_read_b128 are bank-conflict-free (R9 had 5.47M conflict cy).

#define BB 64
#define NN 197
#define CC 768
#define HH 12
#define DD 64
#define KEEP 160
#define SCALE_F 0.125f   // 64^-0.5
#define OUT0_ELEMS ((size_t)BB * NN * CC)   // 9,682,944
#define VST 212          // LDS row stride (u16): 8B-aligned rows, gcd(106,32)=2

typedef __attribute__((ext_vector_type(8))) short bf16x8_t;
typedef __attribute__((ext_vector_type(4))) float f32x4_t;

__device__ __forceinline__ float b2f(unsigned short u) {
  union { unsigned u; float f; } cv; cv.u = (unsigned)u << 16; return cv.f;
}
__device__ __forceinline__ unsigned short f2b(float f) {   // RNE, finite
  union { float f; unsigned u; } cv; cv.f = f;
  return (unsigned short)((cv.u + 0x7FFFu + ((cv.u >> 16) & 1u)) >> 16);
}
__device__ __forceinline__ float ldmix(const void* p, size_t i, int f32) {
  return f32 ? ((const float*)p)[i] : b2f(((const unsigned short*)p)[i]);
}
// 8 bf16 from LDS via two b64 reads (rows only 8B-aligned at VST=212)
__device__ __forceinline__ bf16x8_t ld8(const unsigned short* p) {
  short4 a = *(const short4*)p;
  short4 b = *(const short4*)(p + 4);
  bf16x8_t v = {a.x, a.y, a.z, a.w, b.x, b.y, b.z, b.w};
  return v;
}

// ---------------------------------------------------------------------------
__global__ void detect_kernel(const void* x, int* flag) {
  __shared__ int cnt;
  if (threadIdx.x == 0) cnt = 0;
  __syncthreads();
  const unsigned short* u = (const unsigned short*)x;
  int wild = 0;
  for (int i = threadIdx.x; i < 4096; i += 256) {
    int e = (u[i] >> 7) & 0xFF;
    wild += (e >= 140);
  }
  atomicAdd(&cnt, wild);
  __syncthreads();
  if (threadIdx.x == 0) *flag = (cnt > 100) ? 1 : 0;
}

__global__ void cvt_all(const void* qkv_w, const void* proj_w, const void* proj_b,
                        unsigned short* wb, unsigned short* pw, float* pbf,
                        const int* flag) {
  const int W3 = 3 * CC * CC, W1 = CC * CC;
  int i = blockIdx.x * 256 + threadIdx.x;
  const int f32 = *flag;
  if (i < W3) {
    wb[i] = f32 ? f2b(((const float*)qkv_w)[i]) : ((const unsigned short*)qkv_w)[i];
  } else if (i < W3 + W1) {
    int j = i - W3;
    pw[j] = f32 ? f2b(((const float*)proj_w)[j]) : ((const unsigned short*)proj_w)[j];
  } else if (i < W3 + W1 + CC) {
    int j = i - W3 - W1;
    pbf[j] = ldmix(proj_b, j, f32);
  }
}

// convert a chunk of x to bf16, 8 elems/thread
__global__ void cvt_x(const void* __restrict__ x, size_t elem_off,
                      unsigned short* __restrict__ xb, int n8,
                      const int* __restrict__ flag) {
  const int i = blockIdx.x * 256 + threadIdx.x;
  if (i >= n8) return;
  const size_t src = elem_off + (size_t)i * 8;
  bf16x8_t v;
  if (*flag) {
    const float* xp = (const float*)x + src;
    float4 u0 = *(const float4*)xp;
    float4 u1 = *(const float4*)(xp + 4);
    v = bf16x8_t{(short)f2b(u0.x), (short)f2b(u0.y), (short)f2b(u0.z),
                 (short)f2b(u0.w), (short)f2b(u1.x), (short)f2b(u1.y),
                 (short)f2b(u1.z), (short)f2b(u1.w)};
  } else {
    v = *(const bf16x8_t*)((const unsigned short*)x + src);
  }
  *(bf16x8_t*)(xb + (size_t)i * 8) = v;
}

// ---------------------------------------------------------------------------
// GEMM LDS layout (per 16x32 chunk, u16): element (row,kg8) at
// chunk*512 + (kg8*16 + row)*8. Staging wave writes 1KB contiguous
// (conflict-free); frag read at chunk*512 + quad*128 + l16*8 hits all 32
// banks exactly 8x per b128 (conflict-free).
// ---------------------------------------------------------------------------

// qkv_gemm: 128x128 LDS-staged MFMA GEMM on bf16 xb @ wb^T. XCD-swizzled.
__global__ __launch_bounds__(256, 6) void qkv_gemm(
    const unsigned short* __restrict__ xb,
    const unsigned short* __restrict__ wb,
    unsigned short* __restrict__ qkvc, int Mc, int bc, int nRow) {
  const int xcd = blockIdx.x & 7;
  const int seq = blockIdx.x >> 3;
  const int colt = seq % 18;
  const int rowt = (seq / 18) * 8 + xcd;
  if (rowt >= nRow) return;
  const int m0 = rowt * 128;
  const int n0 = colt * 128;

  __shared__ unsigned short As[4096];
  __shared__ unsigned short Bs[4096];
  const int lane = threadIdx.x & 63;
  const int wave = threadIdx.x >> 6;
  const int l16  = lane & 15;
  const int quad = lane >> 4;
  const int wm = wave >> 1, wn = wave & 1;
  f32x4_t acc[4][4] = {};
  for (int kt = 0; kt < 24; kt++) {
    const int k0 = kt * 32;
    __syncthreads();
    #pragma unroll
    for (int j = 0; j < 2; j++) {
      const int chunk = wave + j * 4;          // slot s = tid + j*256
      const int row = lane & 15, kg = lane >> 4;
      int grA = m0 + chunk * 16 + row; if (grA >= Mc) grA = Mc - 1;
      *(bf16x8_t*)&As[chunk * 512 + lane * 8] =
          *(const bf16x8_t*)(xb + (size_t)grA * CC + k0 + kg * 8);
      const int grB = n0 + chunk * 16 + row;
      *(bf16x8_t*)&Bs[chunk * 512 + lane * 8] =
          *(const bf16x8_t*)(wb + (size_t)grB * CC + k0 + kg * 8);
    }
    __syncthreads();
    bf16x8_t afr[4], bfr[4];
    #pragma unroll
    for (int r = 0; r < 4; r++)
      afr[r] = *(const bf16x8_t*)&As[(wm * 4 + r) * 512 + quad * 128 + l16 * 8];
    #pragma unroll
    for (int c = 0; c < 4; c++)
      bfr[c] = *(const bf16x8_t*)&Bs[(wn * 4 + c) * 512 + quad * 128 + l16 * 8];
    #pragma unroll
    for (int r = 0; r < 4; r++)
      #pragma unroll
      for (int c = 0; c < 4; c++)
        acc[r][c] = __builtin_amdgcn_mfma_f32_16x16x32_bf16(afr[r], bfr[c],
                                                            acc[r][c], 0, 0, 0);
  }
  #pragma unroll
  for (int c = 0; c < 4; c++) {
    const int col = n0 + wn * 64 + c * 16 + l16;
    const int s = col / CC;
    const int rem = col - s * CC;
    const int hc = rem >> 6, d = rem & 63;
    #pragma unroll
    for (int r = 0; r < 4; r++) {
      #pragma unroll
      for (int i = 0; i < 4; i++) {
        const int m = m0 + wm * 64 + r * 16 + quad * 4 + i;
        if (m < Mc) {
          const int bb = m / NN, n = m - bb * NN;
          qkvc[((((size_t)s * bc + bb) * HH + hc) * NN + n) * DD + d] =
              f2b(acc[r][c][i]);
        }
      }
    }
  }
}

// proj_gemm: same structure, 6 col-tiles, dual-dtype store.
__global__ __launch_bounds__(256, 6) void proj_gemm(
    const unsigned short* __restrict__ Yc,
    const unsigned short* __restrict__ pw,
    const float* __restrict__ pbf,
    void* __restrict__ out, size_t out_off, int Mc, int nRow,
    const int* __restrict__ flag) {
  const int xcd = blockIdx.x & 7;
  const int seq = blockIdx.x >> 3;
  const int colt = seq % 6;
  const int rowt = (seq / 6) * 8 + xcd;
  if (rowt >= nRow) return;
  const int m0 = rowt * 128;
  const int n0 = colt * 128;

  __shared__ unsigned short As[4096];
  __shared__ unsigned short Bs[4096];
  const int lane = threadIdx.x & 63;
  const int wave = threadIdx.x >> 6;
  const int l16  = lane & 15;
  const int quad = lane >> 4;
  const int wm = wave >> 1, wn = wave & 1;
  f32x4_t acc[4][4] = {};
  for (int kt = 0; kt < 24; kt++) {
    const int k0 = kt * 32;
    __syncthreads();
    #pragma unroll
    for (int j = 0; j < 2; j++) {
      const int chunk = wave + j * 4;
      const int row = lane & 15, kg = lane >> 4;
      int grA = m0 + chunk * 16 + row; if (grA >= Mc) grA = Mc - 1;
      *(bf16x8_t*)&As[chunk * 512 + lane * 8] =
          *(const bf16x8_t*)(Yc + (size_t)grA * CC + k0 + kg * 8);
      const int grB = n0 + chunk * 16 + row;
      *(bf16x8_t*)&Bs[chunk * 512 + lane * 8] =
          *(const bf16x8_t*)(pw + (size_t)grB * CC + k0 + kg * 8);
    }
    __syncthreads();
    bf16x8_t afr[4], bfr[4];
    #pragma unroll
    for (int r = 0; r < 4; r++)
      afr[r] = *(const bf16x8_t*)&As[(wm * 4 + r) * 512 + quad * 128 + l16 * 8];
    #pragma unroll
    for (int c = 0; c < 4; c++)
      bfr[c] = *(const bf16x8_t*)&Bs[(wn * 4 + c) * 512 + quad * 128 + l16 * 8];
    #pragma unroll
    for (int r = 0; r < 4; r++)
      #pragma unroll
      for (int c = 0; c < 4; c++)
        acc[r][c] = __builtin_amdgcn_mfma_f32_16x16x32_bf16(afr[r], bfr[c],
                                                            acc[r][c], 0, 0, 0);
  }
  const int f32 = *flag;
  #pragma unroll
  for (int c = 0; c < 4; c++) {
    const int col = n0 + wn * 64 + c * 16 + l16;
    const float bv = pbf[col];
    #pragma unroll
    for (int r = 0; r < 4; r++) {
      #pragma unroll
      for (int i = 0; i < 4; i++) {
        const int m = m0 + wm * 64 + r * 16 + quad * 4 + i;
        if (m < Mc) {
          const float val = acc[r][c][i] + bv;
          const size_t oi = out_off + (size_t)m * CC + col;
          if (f32) ((float*)out)[oi] = val;
          else ((unsigned short*)out)[oi] = f2b(val);
        }
      }
    }
  }
}

// ---------------------------------------------------------------------------
// MFMA attention (R7/R8 structure). Grid (bc*HH); 4 waves/block; each wave
// loops q-strips si = it*4+wave (13 strips of 16 rows). LDS 54,272 B.
// ---------------------------------------------------------------------------
__global__ __launch_bounds__(256, 3) void attn_kernel(
    const unsigned short* __restrict__ qkvc, int bc,
    unsigned short* __restrict__ Yc) {
  const int bh = blockIdx.x;
  const int bb = bh / HH;
  const int h  = bh % HH;
  const size_t mat = (size_t)bc * HH * NN * DD;
  const unsigned short* q = qkvc + ((size_t)bb * HH + h) * NN * DD;
  const unsigned short* k = q + mat;
  const unsigned short* v = q + 2 * mat;

  __shared__ unsigned short Vt[DD * VST];     // 27,136 B (V^T, zero-padded)
  __shared__ unsigned short Pl[4][16 * VST];  // 27,136 B (per-wave P strip)

  const int lane = threadIdx.x & 63;
  const int wave = threadIdx.x >> 6;
  const int l16  = lane & 15;
  const int quad = lane >> 4;

  // stage V^T once: Vt[d=lane][key], keys 197..211 zeroed
  #pragma unroll
  for (int it = 0; it < 53; it++) {
    const int key = it * 4 + wave;
    unsigned short val = (key < NN) ? v[(size_t)key * DD + lane]
                                    : (unsigned short)0;
    Vt[lane * VST + key] = val;
  }
  __syncthreads();

  unsigned short* Pw = &Pl[wave][0];

  for (int it = 0; it < 4; it++) {
    const int si = it * 4 + wave;
    if (si >= 13) break;          // no barriers inside the loop: safe
    const int q0 = si * 16;

    int qrow = q0 + l16; if (qrow >= NN) qrow = NN - 1;
    const unsigned short* qp = q + (size_t)qrow * DD + quad * 8;
    const bf16x8_t aq0 = *(const bf16x8_t*)qp;
    const bf16x8_t aq1 = *(const bf16x8_t*)(qp + 32);

    // S strip: 16 q-rows x 208 keys, 26 MFMAs, K frags from global (L1/L2)
    f32x4_t sc[13];
    #pragma unroll
    for (int ct = 0; ct < 13; ct++) {
      int key = ct * 16 + l16; if (key >= NN) key = NN - 1;
      const unsigned short* kp = k + (size_t)key * DD + quad * 8;
      const bf16x8_t b0 = *(const bf16x8_t*)kp;
      const bf16x8_t b1 = *(const bf16x8_t*)(kp + 32);
      f32x4_t t = {0.f, 0.f, 0.f, 0.f};
      t = __builtin_amdgcn_mfma_f32_16x16x32_bf16(aq0, b0, t, 0, 0, 0);
      t = __builtin_amdgcn_mfma_f32_16x16x32_bf16(aq1, b1, t, 0, 0, 0);
      sc[ct] = t;
    }

    // softmax per row (row = quad*4+i), reduce across l16 via shfl
    float inv_l[4];
    #pragma unroll
    for (int i = 0; i < 4; i++) {
      float m = -1e30f;
      #pragma unroll
      for (int ct = 0; ct < 13; ct++)
        if (ct < 12 || l16 < 5) m = fmaxf(m, sc[ct][i] * SCALE_F);
      #pragma unroll
      for (int d = 1; d < 16; d <<= 1) m = fmaxf(m, __shfl_xor(m, d, 64));
      float s = 0.f;
      #pragma unroll
      for (int ct = 0; ct < 13; ct++) {
        const float p = (ct < 12 || l16 < 5) ? __expf(sc[ct][i] * SCALE_F - m)
                                             : 0.f;
        sc[ct][i] = p;
        s += p;
      }
      #pragma unroll
      for (int d = 1; d < 16; d <<= 1) s += __shfl_xor(s, d, 64);
      inv_l[i] = 1.0f / s;
    }

    // P -> per-wave LDS (A-layout, cols 0..207); same-wave ordering only
    #pragma unroll
    for (int i = 0; i < 4; i++) {
      const int ro = (quad * 4 + i) * VST;
      #pragma unroll
      for (int ct = 0; ct < 13; ct++)
        Pw[ro + ct * 16 + l16] = f2b(sc[ct][i]);
    }

    // O strip = P(16x208) @ V(208x64): 6 full 32-key chunks + 16-key tail
    f32x4_t oc[4] = {};
    #pragma unroll
    for (int ks = 0; ks < 6; ks++) {
      const bf16x8_t ap = ld8(&Pw[l16 * VST + ks * 32 + quad * 8]);
      #pragma unroll
      for (int dt = 0; dt < 4; dt++) {
        const bf16x8_t bv = ld8(&Vt[(dt * 16 + l16) * VST + ks * 32 + quad * 8]);
        oc[dt] = __builtin_amdgcn_mfma_f32_16x16x32_bf16(ap, bv, oc[dt], 0, 0, 0);
      }
    }
    {  // tail keys 192..207: quads 0,1 carry data, quads 2,3 zero frags
      const bf16x8_t zz = {};
      bf16x8_t ap = zz;
      if (quad < 2) ap = ld8(&Pw[l16 * VST + 192 + quad * 8]);
      #pragma unroll
      for (int dt = 0; dt < 4; dt++) {
        bf16x8_t bv = zz;
        if (quad < 2) bv = ld8(&Vt[(dt * 16 + l16) * VST + 192 + quad * 8]);
        oc[dt] = __builtin_amdgcn_mfma_f32_16x16x32_bf16(ap, bv, oc[dt], 0, 0, 0);
      }
    }

    #pragma unroll
    for (int i = 0; i < 4; i++) {
      const int n = q0 + quad * 4 + i;
      if (n < NN) {
        unsigned short* yp = Yc + ((size_t)bb * NN + n) * CC + h * DD;
        #pragma unroll
        for (int dt = 0; dt < 4; dt++)
          yp[dt * 16 + l16] = f2b(oc[dt][i] * inv_l[i]);
      }
    }
  }
}

// ---------------------------------------------------------------------------
// Top-k path, fp32-exact (matches np reference ranking).
// ---------------------------------------------------------------------------
__global__ __launch_bounds__(256, 4) void qcls_kernel(
    const void* __restrict__ x, const void* __restrict__ qkv_w,
    float* __restrict__ qc, const int* __restrict__ flag) {
  const int idx = blockIdx.x * 4 + (threadIdx.x >> 6);
  if (idx >= BB * CC) return;
  const int b = idx / CC, i = idx - b * CC;
  const int lane = threadIdx.x & 63;
  const int f32 = *flag;
  const size_t xr = (size_t)b * NN * CC;
  const size_t wr = (size_t)i * CC;
  float p = 0.f;
  #pragma unroll
  for (int j = 0; j < 12; j++)
    p += ldmix(x, xr + j * 64 + lane, f32) * ldmix(qkv_w, wr + j * 64 + lane, f32);
  #pragma unroll
  for (int m = 32; m; m >>= 1) p += __shfl_xor(p, m, 64);
  if (lane == 0) qc[(size_t)b * CC + i] = p;
}

__global__ __launch_bounds__(256, 4) void gmat_kernel(
    const void* __restrict__ qkv_w, const float* __restrict__ qc,
    float* __restrict__ g, const int* __restrict__ flag) {
  const int b = blockIdx.x, h = blockIdx.y;
  const int f32 = *flag;
  __shared__ float qh[DD];
  if (threadIdx.x < DD) qh[threadIdx.x] = qc[(size_t)b * CC + h * DD + threadIdx.x];
  __syncthreads();
  const int c0 = threadIdx.x, c1 = c0 + 256, c2 = c1 + 256;
  float a0 = 0.f, a1 = 0.f, a2 = 0.f;
  for (int d = 0; d < DD; d++) {
    const size_t ro = (size_t)(CC + h * DD + d) * CC;
    const float qv = qh[d];
    a0 += ldmix(qkv_w, ro + c0, f32) * qv;
    a1 += ldmix(qkv_w, ro + c1, f32) * qv;
    a2 += ldmix(qkv_w, ro + c2, f32) * qv;
  }
  float* gb = g + ((size_t)b * HH + h) * CC;
  gb[c0] = a0; gb[c1] = a1; gb[c2] = a2;
}

__global__ __launch_bounds__(256, 4) void score_kernel(
    const void* __restrict__ x, const float* __restrict__ g,
    float* __restrict__ wscore, const int* __restrict__ flag) {
  const int idx = blockIdx.x * 4 + (threadIdx.x >> 6);
  if (idx >= BB * NN) return;
  const int b = idx / NN, n = idx - b * NN;
  const int lane = threadIdx.x & 63;
  const int f32 = *flag;
  const size_t xr = ((size_t)b * NN + n) * CC;
  float xv[12];
  #pragma unroll
  for (int j = 0; j < 12; j++) xv[j] = ldmix(x, xr + j * 64 + lane, f32);
  const float* gb = g + (size_t)b * HH * CC;
  float acc = 0.f;
  #pragma unroll
  for (int h = 0; h < HH; h++) {
    const float* gh = gb + (size_t)h * CC;
    float p = 0.f;
    #pragma unroll
    for (int j = 0; j < 12; j++) p += xv[j] * gh[j * 64 + lane];
    #pragma unroll
    for (int m = 32; m; m >>= 1) p += __shfl_xor(p, m, 64);
    acc += fabsf(p);
  }
  if (lane == 0) wscore[(size_t)b * NN + n] = acc;
}

__global__ __launch_bounds__(256, 4) void rank_kernel(
    const float* __restrict__ wscore, void* __restrict__ out,
    const int* __restrict__ flag) {
  const int b = blockIdx.x;
  const int f32 = *flag;
  __shared__ float wgt[NN];
  __shared__ int   rank[NN];
  if (threadIdx.x < NN) wgt[threadIdx.x] = wscore[(size_t)b * NN + threadIdx.x];
  __syncthreads();
  const int n = threadIdx.x;
  if (n < NN) {
    float wi = wgt[n];
    int rk = 0;
    for (int j = 0; j < NN; j++) {
      float wj = wgt[j];
      rk += (wj > wi) || (wj == wi && j < n);   // stable top_k tie-break
    }
    rank[n] = rk;
  }
  __syncthreads();
  if (n < NN && rank[n] < KEEP) {
    int pos = 0;
    for (int j = 0; j < n; j++) pos += (rank[j] < KEEP);
    const size_t oi = OUT0_ELEMS + (size_t)b * KEEP + pos;
    if (f32) ((float*)out)[oi] = (float)n;
    else ((unsigned short*)out)[oi] = f2b((float)n);
  }
}

// ---------------------------------------------------------------------------
extern "C" void kernel_launch(void* const* d_in, const int* in_sizes, int n_in,
                              void* d_out, int out_size, void* d_ws, size_t ws_size,
                              hipStream_t stream) {
  const void* x      = d_in[0];
  const void* qkv_w  = d_in[1];
  const void* proj_w = d_in[2];
  const void* proj_b = d_in[3];

  char* wsb = (char*)d_ws;
  int* flag = (int*)wsb;
  unsigned short* wb  = (unsigned short*)(wsb + 256);
  unsigned short* pw  = (unsigned short*)(wsb + 256 + 3538944);
  float* pbf    = (float*)(wsb + 256 + 3538944 + 1179648);
  float* qc     = (float*)(wsb + 256 + 3538944 + 1179648 + 4096);
  float* g      = qc + (size_t)BB * CC;
  float* wscore = g + (size_t)BB * HH * CC;
  const size_t fixed = 256 + 3538944 + 1179648 + 4096 + 196608 + 2359296 + 51200;
  char* chunk = wsb + fixed;

  const size_t per_batch = (size_t)NN * CC * 2       // xb_c
                         + 3ull * HH * NN * DD * 2   // qkvc
                         + (size_t)NN * CC * 2;      // Yc  = 1,512,960
  int Bc = BB;
  while (Bc > 1 && fixed + (size_t)Bc * per_batch > ws_size) Bc >>= 1;

  unsigned short* xb   = (unsigned short*)chunk;
  unsigned short* qkvc = xb + (size_t)Bc * NN * CC;
  unsigned short* Yc   = qkvc + 3ull * Bc * HH * NN * DD;

  detect_kernel<<<1, 256, 0, stream>>>(x, flag);
  const int cvt_n = 3 * CC * CC + CC * CC + CC;
  cvt_all<<<(cvt_n + 255) / 256, 256, 0, stream>>>(qkv_w, proj_w, proj_b,
                                                   wb, pw, pbf, flag);

  // top-k path (fp32-exact, independent of the bf16 pipeline)
  qcls_kernel<<<(BB * CC + 3) / 4, 256, 0, stream>>>(x, qkv_w, qc, flag);
  gmat_kernel<<<dim3(BB, HH), 256, 0, stream>>>(qkv_w, qc, g, flag);
  score_kernel<<<(BB * NN + 3) / 4, 256, 0, stream>>>(x, g, wscore, flag);
  rank_kernel<<<BB, 256, 0, stream>>>(wscore, d_out, flag);

  const int nChunks = (BB + Bc - 1) / Bc;
  for (int cb = 0; cb < nChunks; cb++) {
    const int b0 = cb * Bc;
    const int bc = (BB - b0 < Bc) ? (BB - b0) : Bc;
    const int Mc = bc * NN;
    const int n8 = Mc * CC / 8;   // Mc*CC is a multiple of 8 (CC=768)
    cvt_x<<<(n8 + 255) / 256, 256, 0, stream>>>(
        x, (size_t)b0 * NN * CC, xb, n8, flag);
    const int nRowQ = (Mc + 127) / 128;
    const int gridQ = 8 * 18 * ((nRowQ + 7) / 8);
    qkv_gemm<<<gridQ, 256, 0, stream>>>(xb, wb, qkvc, Mc, bc, nRowQ);
    attn_kernel<<<dim3(bc * HH), 256, 0, stream>>>(qkvc, bc, Yc);
    const int gridP = 8 * 6 * ((nRowQ + 7) / 8);
    proj_gemm<<<gridP, 256, 0, stream>>>(
        Yc, pw, pbf, d_out, (size_t)b0 * NN * CC, Mc, nRowQ, flag);
  }
}

// Round 12
// 619.504 us; speedup vs baseline: 1.5418x; 1.5418x over previous
//
#include <hip/hip_runtime.h>
#include <hip/hip_bf16.h>

// PoolingAttention: B=64 N=197 C=768 H=12 D=64. fp32 in/out (runtime-detected).
// out = [B*N*C] attention output ++ [B*160] keep_index.
//
// R12: GEMMs reverted verbatim to R9 (bounds=4 + ch-staging). R10/R11's
// FETCH explosion (38->705MB) was the bounds-6 occupancy raise collapsing
// per-XCD L2 reuse (working set 5.5MB > 4MB), NOT global_load_lds.
// qcls/gmat rebuilt as weight-stationary 64x64-tiled fp32 GEMMs (weights
// read once, not once per batch: 151MB -> 2.4MB traffic each).

#define BB 64
#define NN 197
#define CC 768
#define HH 12
#define DD 64
#define KEEP 160
#define SCALE_F 0.125f   // 64^-0.5
#define OUT0_ELEMS ((size_t)BB * NN * CC)   // 9,682,944
#define VST 212          // LDS row stride (u16): 8B-aligned rows

typedef __attribute__((ext_vector_type(8))) short bf16x8_t;
typedef __attribute__((ext_vector_type(4))) float f32x4_t;

__device__ __forceinline__ float b2f(unsigned short u) {
  union { unsigned u; float f; } cv; cv.u = (unsigned)u << 16; return cv.f;
}
__device__ __forceinline__ unsigned short f2b(float f) {   // RNE, finite
  union { float f; unsigned u; } cv; cv.f = f;
  return (unsigned short)((cv.u + 0x7FFFu + ((cv.u >> 16) & 1u)) >> 16);
}
__device__ __forceinline__ float ldmix(const void* p, size_t i, int f32) {
  return f32 ? ((const float*)p)[i] : b2f(((const unsigned short*)p)[i]);
}
__device__ __forceinline__ bf16x8_t ld8(const unsigned short* p) {
  short4 a = *(const short4*)p;
  short4 b = *(const short4*)(p + 4);
  bf16x8_t v = {a.x, a.y, a.z, a.w, b.x, b.y, b.z, b.w};
  return v;
}

// ---------------------------------------------------------------------------
__global__ void detect_kernel(const void* x, int* flag) {
  __shared__ int cnt;
  if (threadIdx.x == 0) cnt = 0;
  __syncthreads();
  const unsigned short* u = (const unsigned short*)x;
  int wild = 0;
  for (int i = threadIdx.x; i < 4096; i += 256) {
    int e = (u[i] >> 7) & 0xFF;
    wild += (e >= 140);
  }
  atomicAdd(&cnt, wild);
  __syncthreads();
  if (threadIdx.x == 0) *flag = (cnt > 100) ? 1 : 0;
}

__global__ void cvt_all(const void* qkv_w, const void* proj_w, const void* proj_b,
                        unsigned short* wb, unsigned short* pw, float* pbf,
                        const int* flag) {
  const int W3 = 3 * CC * CC, W1 = CC * CC;
  int i = blockIdx.x * 256 + threadIdx.x;
  const int f32 = *flag;
  if (i < W3) {
    wb[i] = f32 ? f2b(((const float*)qkv_w)[i]) : ((const unsigned short*)qkv_w)[i];
  } else if (i < W3 + W1) {
    int j = i - W3;
    pw[j] = f32 ? f2b(((const float*)proj_w)[j]) : ((const unsigned short*)proj_w)[j];
  } else if (i < W3 + W1 + CC) {
    int j = i - W3 - W1;
    pbf[j] = ldmix(proj_b, j, f32);
  }
}

__global__ void cvt_x(const void* __restrict__ x, size_t elem_off,
                      unsigned short* __restrict__ xb, int n8,
                      const int* __restrict__ flag) {
  const int i = blockIdx.x * 256 + threadIdx.x;
  if (i >= n8) return;
  const size_t src = elem_off + (size_t)i * 8;
  bf16x8_t v;
  if (*flag) {
    const float* xp = (const float*)x + src;
    float4 u0 = *(const float4*)xp;
    float4 u1 = *(const float4*)(xp + 4);
    v = bf16x8_t{(short)f2b(u0.x), (short)f2b(u0.y), (short)f2b(u0.z),
                 (short)f2b(u0.w), (short)f2b(u1.x), (short)f2b(u1.y),
                 (short)f2b(u1.z), (short)f2b(u1.w)};
  } else {
    v = *(const bf16x8_t*)((const unsigned short*)x + src);
  }
  *(bf16x8_t*)(xb + (size_t)i * 8) = v;
}

// ---------------------------------------------------------------------------
// qkv_gemm: 128x128 LDS-staged MFMA GEMM (R9-verbatim structure). XCD-swizzled.
// ---------------------------------------------------------------------------
__global__ __launch_bounds__(256, 4) void qkv_gemm(
    const unsigned short* __restrict__ xb,
    const unsigned short* __restrict__ wb,
    unsigned short* __restrict__ qkvc, int Mc, int bc, int nRow) {
  const int xcd = blockIdx.x & 7;
  const int seq = blockIdx.x >> 3;
  const int colt = seq % 18;
  const int rowt = (seq / 18) * 8 + xcd;
  if (rowt >= nRow) return;
  const int m0 = rowt * 128;
  const int n0 = colt * 128;

  __shared__ unsigned short As[4096];
  __shared__ unsigned short Bs[4096];
  const int lane = threadIdx.x & 63;
  const int wave = threadIdx.x >> 6;
  const int l16  = lane & 15;
  const int quad = lane >> 4;
  const int wm = wave >> 1, wn = wave & 1;
  f32x4_t acc[4][4] = {};
  for (int kt = 0; kt < 24; kt++) {
    const int k0 = kt * 32;
    __syncthreads();
    #pragma unroll
    for (int ch = threadIdx.x; ch < 512; ch += 256) {
      int row = ch >> 2, kg = ch & 3;
      int gr = m0 + row; if (gr >= Mc) gr = Mc - 1;
      *(bf16x8_t*)&As[(row >> 4) * 512 + (row & 15) * 32 + kg * 8] =
          *(const bf16x8_t*)(xb + (size_t)gr * CC + k0 + kg * 8);
    }
    #pragma unroll
    for (int ch = threadIdx.x; ch < 512; ch += 256) {
      int row = ch >> 2, kg = ch & 3;
      *(bf16x8_t*)&Bs[(row >> 4) * 512 + (row & 15) * 32 + kg * 8] =
          *(const bf16x8_t*)(wb + (size_t)(n0 + row) * CC + k0 + kg * 8);
    }
    __syncthreads();
    bf16x8_t afr[4], bfr[4];
    #pragma unroll
    for (int r = 0; r < 4; r++)
      afr[r] = *(const bf16x8_t*)&As[(wm * 4 + r) * 512 + l16 * 32 + quad * 8];
    #pragma unroll
    for (int c = 0; c < 4; c++)
      bfr[c] = *(const bf16x8_t*)&Bs[(wn * 4 + c) * 512 + l16 * 32 + quad * 8];
    #pragma unroll
    for (int r = 0; r < 4; r++)
      #pragma unroll
      for (int c = 0; c < 4; c++)
        acc[r][c] = __builtin_amdgcn_mfma_f32_16x16x32_bf16(afr[r], bfr[c],
                                                            acc[r][c], 0, 0, 0);
  }
  #pragma unroll
  for (int c = 0; c < 4; c++) {
    const int col = n0 + wn * 64 + c * 16 + l16;
    const int s = col / CC;
    const int rem = col - s * CC;
    const int hc = rem >> 6, d = rem & 63;
    #pragma unroll
    for (int r = 0; r < 4; r++) {
      #pragma unroll
      for (int i = 0; i < 4; i++) {
        const int m = m0 + wm * 64 + r * 16 + quad * 4 + i;
        if (m < Mc) {
          const int bb = m / NN, n = m - bb * NN;
          qkvc[((((size_t)s * bc + bb) * HH + hc) * NN + n) * DD + d] =
              f2b(acc[r][c][i]);
        }
      }
    }
  }
}

// ---------------------------------------------------------------------------
// proj_gemm: R9-verbatim structure, 6 col-tiles, dual-dtype store.
// ---------------------------------------------------------------------------
__global__ __launch_bounds__(256, 4) void proj_gemm(
    const unsigned short* __restrict__ Yc,
    const unsigned short* __restrict__ pw,
    const float* __restrict__ pbf,
    void* __restrict__ out, size_t out_off, int Mc, int nRow,
    const int* __restrict__ flag) {
  const int xcd = blockIdx.x & 7;
  const int seq = blockIdx.x >> 3;
  const int colt = seq % 6;
  const int rowt = (seq / 6) * 8 + xcd;
  if (rowt >= nRow) return;
  const int m0 = rowt * 128;
  const int n0 = colt * 128;

  __shared__ unsigned short As[4096];
  __shared__ unsigned short Bs[4096];
  const int lane = threadIdx.x & 63;
  const int wave = threadIdx.x >> 6;
  const int l16  = lane & 15;
  const int quad = lane >> 4;
  const int wm = wave >> 1, wn = wave & 1;
  f32x4_t acc[4][4] = {};
  for (int kt = 0; kt < 24; kt++) {
    const int k0 = kt * 32;
    __syncthreads();
    #pragma unroll
    for (int ch = threadIdx.x; ch < 512; ch += 256) {
      int row = ch >> 2, kg = ch & 3;
      int gr = m0 + row; if (gr >= Mc) gr = Mc - 1;
      *(bf16x8_t*)&As[(row >> 4) * 512 + (row & 15) * 32 + kg * 8] =
          *(const bf16x8_t*)(Yc + (size_t)gr * CC + k0 + kg * 8);
    }
    #pragma unroll
    for (int ch = threadIdx.x; ch < 512; ch += 256) {
      int row = ch >> 2, kg = ch & 3;
      *(bf16x8_t*)&Bs[(row >> 4) * 512 + (row & 15) * 32 + kg * 8] =
          *(const bf16x8_t*)(pw + (size_t)(n0 + row) * CC + k0 + kg * 8);
    }
    __syncthreads();
    bf16x8_t afr[4], bfr[4];
    #pragma unroll
    for (int r = 0; r < 4; r++)
      afr[r] = *(const bf16x8_t*)&As[(wm * 4 + r) * 512 + l16 * 32 + quad * 8];
    #pragma unroll
    for (int c = 0; c < 4; c++)
      bfr[c] = *(const bf16x8_t*)&Bs[(wn * 4 + c) * 512 + l16 * 32 + quad * 8];
    #pragma unroll
    for (int r = 0; r < 4; r++)
      #pragma unroll
      for (int c = 0; c < 4; c++)
        acc[r][c] = __builtin_amdgcn_mfma_f32_16x16x32_bf16(afr[r], bfr[c],
                                                            acc[r][c], 0, 0, 0);
  }
  const int f32 = *flag;
  #pragma unroll
  for (int c = 0; c < 4; c++) {
    const int col = n0 + wn * 64 + c * 16 + l16;
    const float bv = pbf[col];
    #pragma unroll
    for (int r = 0; r < 4; r++) {
      #pragma unroll
      for (int i = 0; i < 4; i++) {
        const int m = m0 + wm * 64 + r * 16 + quad * 4 + i;
        if (m < Mc) {
          const float val = acc[r][c][i] + bv;
          const size_t oi = out_off + (size_t)m * CC + col;
          if (f32) ((float*)out)[oi] = val;
          else ((unsigned short*)out)[oi] = f2b(val);
        }
      }
    }
  }
}

// ---------------------------------------------------------------------------
// MFMA attention (R7/R8 structure, unchanged).
// ---------------------------------------------------------------------------
__global__ __launch_bounds__(256, 3) void attn_kernel(
    const unsigned short* __restrict__ qkvc, int bc,
    unsigned short* __restrict__ Yc) {
  const int bh = blockIdx.x;
  const int bb = bh / HH;
  const int h  = bh % HH;
  const size_t mat = (size_t)bc * HH * NN * DD;
  const unsigned short* q = qkvc + ((size_t)bb * HH + h) * NN * DD;
  const unsigned short* k = q + mat;
  const unsigned short* v = q + 2 * mat;

  __shared__ unsigned short Vt[DD * VST];     // 27,136 B
  __shared__ unsigned short Pl[4][16 * VST];  // 27,136 B

  const int lane = threadIdx.x & 63;
  const int wave = threadIdx.x >> 6;
  const int l16  = lane & 15;
  const int quad = lane >> 4;

  #pragma unroll
  for (int it = 0; it < 53; it++) {
    const int key = it * 4 + wave;
    unsigned short val = (key < NN) ? v[(size_t)key * DD + lane]
                                    : (unsigned short)0;
    Vt[lane * VST + key] = val;
  }
  __syncthreads();

  unsigned short* Pw = &Pl[wave][0];

  for (int it = 0; it < 4; it++) {
    const int si = it * 4 + wave;
    if (si >= 13) break;
    const int q0 = si * 16;

    int qrow = q0 + l16; if (qrow >= NN) qrow = NN - 1;
    const unsigned short* qp = q + (size_t)qrow * DD + quad * 8;
    const bf16x8_t aq0 = *(const bf16x8_t*)qp;
    const bf16x8_t aq1 = *(const bf16x8_t*)(qp + 32);

    f32x4_t sc[13];
    #pragma unroll
    for (int ct = 0; ct < 13; ct++) {
      int key = ct * 16 + l16; if (key >= NN) key = NN - 1;
      const unsigned short* kp = k + (size_t)key * DD + quad * 8;
      const bf16x8_t b0 = *(const bf16x8_t*)kp;
      const bf16x8_t b1 = *(const bf16x8_t*)(kp + 32);
      f32x4_t t = {0.f, 0.f, 0.f, 0.f};
      t = __builtin_amdgcn_mfma_f32_16x16x32_bf16(aq0, b0, t, 0, 0, 0);
      t = __builtin_amdgcn_mfma_f32_16x16x32_bf16(aq1, b1, t, 0, 0, 0);
      sc[ct] = t;
    }

    float inv_l[4];
    #pragma unroll
    for (int i = 0; i < 4; i++) {
      float m = -1e30f;
      #pragma unroll
      for (int ct = 0; ct < 13; ct++)
        if (ct < 12 || l16 < 5) m = fmaxf(m, sc[ct][i] * SCALE_F);
      #pragma unroll
      for (int d = 1; d < 16; d <<= 1) m = fmaxf(m, __shfl_xor(m, d, 64));
      float s = 0.f;
      #pragma unroll
      for (int ct = 0; ct < 13; ct++) {
        const float p = (ct < 12 || l16 < 5) ? __expf(sc[ct][i] * SCALE_F - m)
                                             : 0.f;
        sc[ct][i] = p;
        s += p;
      }
      #pragma unroll
      for (int d = 1; d < 16; d <<= 1) s += __shfl_xor(s, d, 64);
      inv_l[i] = 1.0f / s;
    }

    #pragma unroll
    for (int i = 0; i < 4; i++) {
      const int ro = (quad * 4 + i) * VST;
      #pragma unroll
      for (int ct = 0; ct < 13; ct++)
        Pw[ro + ct * 16 + l16] = f2b(sc[ct][i]);
    }

    f32x4_t oc[4] = {};
    #pragma unroll
    for (int ks = 0; ks < 6; ks++) {
      const bf16x8_t ap = ld8(&Pw[l16 * VST + ks * 32 + quad * 8]);
      #pragma unroll
      for (int dt = 0; dt < 4; dt++) {
        const bf16x8_t bv = ld8(&Vt[(dt * 16 + l16) * VST + ks * 32 + quad * 8]);
        oc[dt] = __builtin_amdgcn_mfma_f32_16x16x32_bf16(ap, bv, oc[dt], 0, 0, 0);
      }
    }
    {
      const bf16x8_t zz = {};
      bf16x8_t ap = zz;
      if (quad < 2) ap = ld8(&Pw[l16 * VST + 192 + quad * 8]);
      #pragma unroll
      for (int dt = 0; dt < 4; dt++) {
        bf16x8_t bv = zz;
        if (quad < 2) bv = ld8(&Vt[(dt * 16 + l16) * VST + 192 + quad * 8]);
        oc[dt] = __builtin_amdgcn_mfma_f32_16x16x32_bf16(ap, bv, oc[dt], 0, 0, 0);
      }
    }

    #pragma unroll
    for (int i = 0; i < 4; i++) {
      const int n = q0 + quad * 4 + i;
      if (n < NN) {
        unsigned short* yp = Yc + ((size_t)bb * NN + n) * CC + h * DD;
        #pragma unroll
        for (int dt = 0; dt < 4; dt++)
          yp[dt * 16 + l16] = f2b(oc[dt][i] * inv_l[i]);
      }
    }
  }
}

// ---------------------------------------------------------------------------
// Top-k path, fp32-exact. R12: weight-stationary tiled GEMMs.
// qcls: qc[b][i] = x[b,0,:] . Wq[i,:]. One block per 64-col tile (12 blocks);
// all 64 batches in-block; Wq read exactly once chip-wide.
// ---------------------------------------------------------------------------
__global__ __launch_bounds__(256, 2) void qcls_kernel(
    const void* __restrict__ x, const void* __restrict__ qkv_w,
    float* __restrict__ qc, const int* __restrict__ flag) {
  const int ct = blockIdx.x;
  const int f32 = *flag;
  __shared__ float Xs[64 * 68];   // [b][k], +4 pad: conflict-free
  __shared__ float Ws[64 * 68];   // [i_local][k]
  const int tid = threadIdx.x;
  const int tb = tid & 15, ti = tid >> 4;
  float acc[4][4] = {};
  for (int kt = 0; kt < 12; kt++) {
    __syncthreads();
    #pragma unroll
    for (int e = 0; e < 16; e++) {
      const int idx = tid + e * 256;
      const int r = idx >> 6, k = idx & 63;
      Xs[r * 68 + k] = ldmix(x, (size_t)r * NN * CC + kt * 64 + k, f32);
      Ws[r * 68 + k] = ldmix(qkv_w, (size_t)(ct * 64 + r) * CC + kt * 64 + k, f32);
    }
    __syncthreads();
    #pragma unroll
    for (int k4 = 0; k4 < 16; k4++) {
      float4 xv[4], wv[4];
      #pragma unroll
      for (int m = 0; m < 4; m++)
        xv[m] = *(const float4*)&Xs[(tb + 16 * m) * 68 + k4 * 4];
      #pragma unroll
      for (int n = 0; n < 4; n++)
        wv[n] = *(const float4*)&Ws[(ti + 16 * n) * 68 + k4 * 4];
      #pragma unroll
      for (int m = 0; m < 4; m++)
        #pragma unroll
        for (int n = 0; n < 4; n++)
          acc[m][n] += xv[m].x * wv[n].x + xv[m].y * wv[n].y
                     + xv[m].z * wv[n].z + xv[m].w * wv[n].w;
    }
  }
  #pragma unroll
  for (int m = 0; m < 4; m++)
    #pragma unroll
    for (int n = 0; n < 4; n++)
      qc[(size_t)(tb + 16 * m) * CC + ct * 64 + ti + 16 * n] = acc[m][n];
}

// gmat: g[b][h][c] = sum_d Wk[h*64+d][c] * qc[b][h*64+d]. Grid (12 ct, 12 h);
// Wk read once chip-wide.
__global__ __launch_bounds__(256, 2) void gmat_kernel(
    const void* __restrict__ qkv_w, const float* __restrict__ qc,
    float* __restrict__ g, const int* __restrict__ flag) {
  const int ct = blockIdx.x, h = blockIdx.y;
  const int f32 = *flag;
  __shared__ float Qs[64 * 68];   // [b][d]
  __shared__ float Ws[64 * 68];   // [d][c_local]
  const int tid = threadIdx.x;
  #pragma unroll
  for (int e = 0; e < 16; e++) {
    const int idx = tid + e * 256;
    const int r = idx >> 6, k = idx & 63;
    Qs[r * 68 + k] = qc[(size_t)r * CC + h * 64 + k];
    Ws[r * 68 + k] = ldmix(qkv_w, (size_t)(CC + h * 64 + r) * CC + ct * 64 + k, f32);
  }
  __syncthreads();
  const int tb = tid & 15, tc = tid >> 4;
  float acc[4][4] = {};
  for (int d = 0; d < 64; d++) {
    float qv[4], wv[4];
    #pragma unroll
    for (int m = 0; m < 4; m++) qv[m] = Qs[(tb + 16 * m) * 68 + d];
    #pragma unroll
    for (int n = 0; n < 4; n++) wv[n] = Ws[d * 68 + tc + 16 * n];
    #pragma unroll
    for (int m = 0; m < 4; m++)
      #pragma unroll
      for (int n = 0; n < 4; n++)
        acc[m][n] += qv[m] * wv[n];
  }
  #pragma unroll
  for (int m = 0; m < 4; m++)
    #pragma unroll
    for (int n = 0; n < 4; n++)
      g[((size_t)(tb + 16 * m) * HH + h) * CC + ct * 64 + tc + 16 * n] =
          acc[m][n];
}

__global__ __launch_bounds__(256, 4) void score_kernel(
    const void* __restrict__ x, const float* __restrict__ g,
    float* __restrict__ wscore, const int* __restrict__ flag) {
  const int idx = blockIdx.x * 4 + (threadIdx.x >> 6);
  if (idx >= BB * NN) return;
  const int b = idx / NN, n = idx - b * NN;
  const int lane = threadIdx.x & 63;
  const int f32 = *flag;
  const size_t xr = ((size_t)b * NN + n) * CC;
  float xv[12];
  #pragma unroll
  for (int j = 0; j < 12; j++) xv[j] = ldmix(x, xr + j * 64 + lane, f32);
  const float* gb = g + (size_t)b * HH * CC;
  float acc = 0.f;
  #pragma unroll
  for (int h = 0; h < HH; h++) {
    const float* gh = gb + (size_t)h * CC;
    float p = 0.f;
    #pragma unroll
    for (int j = 0; j < 12; j++) p += xv[j] * gh[j * 64 + lane];
    #pragma unroll
    for (int m = 32; m; m >>= 1) p += __shfl_xor(p, m, 64);
    acc += fabsf(p);
  }
  if (lane == 0) wscore[(size_t)b * NN + n] = acc;
}

__global__ __launch_bounds__(256, 4) void rank_kernel(
    const float* __restrict__ wscore, void* __restrict__ out,
    const int* __restrict__ flag) {
  const int b = blockIdx.x;
  const int f32 = *flag;
  __shared__ float wgt[NN];
  __shared__ int   rank[NN];
  if (threadIdx.x < NN) wgt[threadIdx.x] = wscore[(size_t)b * NN + threadIdx.x];
  __syncthreads();
  const int n = threadIdx.x;
  if (n < NN) {
    float wi = wgt[n];
    int rk = 0;
    for (int j = 0; j < NN; j++) {
      float wj = wgt[j];
      rk += (wj > wi) || (wj == wi && j < n);   // stable top_k tie-break
    }
    rank[n] = rk;
  }
  __syncthreads();
  if (n < NN && rank[n] < KEEP) {
    int pos = 0;
    for (int j = 0; j < n; j++) pos += (rank[j] < KEEP);
    const size_t oi = OUT0_ELEMS + (size_t)b * KEEP + pos;
    if (f32) ((float*)out)[oi] = (float)n;
    else ((unsigned short*)out)[oi] = f2b((float)n);
  }
}

// ---------------------------------------------------------------------------
extern "C" void kernel_launch(void* const* d_in, const int* in_sizes, int n_in,
                              void* d_out, int out_size, void* d_ws, size_t ws_size,
                              hipStream_t stream) {
  const void* x      = d_in[0];
  const void* qkv_w  = d_in[1];
  const void* proj_w = d_in[2];
  const void* proj_b = d_in[3];

  char* wsb = (char*)d_ws;
  int* flag = (int*)wsb;
  unsigned short* wb  = (unsigned short*)(wsb + 256);
  unsigned short* pw  = (unsigned short*)(wsb + 256 + 3538944);
  float* pbf    = (float*)(wsb + 256 + 3538944 + 1179648);
  float* qc     = (float*)(wsb + 256 + 3538944 + 1179648 + 4096);
  float* g      = qc + (size_t)BB * CC;
  float* wscore = g + (size_t)BB * HH * CC;
  const size_t fixed = 256 + 3538944 + 1179648 + 4096 + 196608 + 2359296 + 51200;
  char* chunk = wsb + fixed;

  const size_t per_batch = (size_t)NN * CC * 2       // xb_c
                         + 3ull * HH * NN * DD * 2   // qkvc
                         + (size_t)NN * CC * 2;      // Yc  = 1,512,960
  int Bc = BB;
  while (Bc > 1 && fixed + (size_t)Bc * per_batch > ws_size) Bc >>= 1;

  unsigned short* xb   = (unsigned short*)chunk;
  unsigned short* qkvc = xb + (size_t)Bc * NN * CC;
  unsigned short* Yc   = qkvc + 3ull * Bc * HH * NN * DD;

  detect_kernel<<<1, 256, 0, stream>>>(x, flag);
  const int cvt_n = 3 * CC * CC + CC * CC + CC;
  cvt_all<<<(cvt_n + 255) / 256, 256, 0, stream>>>(qkv_w, proj_w, proj_b,
                                                   wb, pw, pbf, flag);

  // top-k path (fp32-exact, weight-stationary tiled GEMMs)
  qcls_kernel<<<12, 256, 0, stream>>>(x, qkv_w, qc, flag);
  gmat_kernel<<<dim3(12, HH), 256, 0, stream>>>(qkv_w, qc, g, flag);
  score_kernel<<<(BB * NN + 3) / 4, 256, 0, stream>>>(x, g, wscore, flag);
  rank_kernel<<<BB, 256, 0, stream>>>(wscore, d_out, flag);

  const int nChunks = (BB + Bc - 1) / Bc;
  for (int cb = 0; cb < nChunks; cb++) {
    const int b0 = cb * Bc;
    const int bc = (BB - b0 < Bc) ? (BB - b0) : Bc;
    const int Mc = bc * NN;
    const int n8 = Mc * CC / 8;
    cvt_x<<<(n8 + 255) / 256, 256, 0, stream>>>(
        x, (size_t)b0 * NN * CC, xb, n8, flag);
    const int nRowQ = (Mc + 127) / 128;
    const int gridQ = 8 * 18 * ((nRowQ + 7) / 8);
    qkv_gemm<<<gridQ, 256, 0, stream>>>(xb, wb, qkvc, Mc, bc, nRowQ);
    attn_kernel<<<dim3(bc * HH), 256, 0, stream>>>(qkvc, bc, Yc);
    const int gridP = 8 * 6 * ((nRowQ + 7) / 8);
    proj_gemm<<<gridP, 256, 0, stream>>>(
        Yc, pw, pbf, d_out, (size_t)b0 * NN * CC, Mc, nRowQ, flag);
  }
}